// Round 8
// baseline (360.286 us; speedup 1.0000x reference)
//
#include <hip/hip_runtime.h>
#include <hip/hip_bf16.h>

typedef __attribute__((ext_vector_type(4))) float f32x4;
typedef __attribute__((ext_vector_type(8))) short bf16x8;
typedef __attribute__((ext_vector_type(8))) unsigned short u16x8;

#define NN 8192
#define SK 16
#define KSL (NN / SK)      // 512 k per WG
#define NC (KSL / 64)      // 8 chunks of 64 k

__device__ __forceinline__ unsigned short f2bf(float f) {
    unsigned int u = __float_as_uint(f);
    u += 0x7fffu + ((u >> 16) & 1u);
    return (unsigned short)(u >> 16);
}

__global__ __launch_bounds__(256) void prep_v(const float* __restrict__ La,
        const float* __restrict__ ve, const float* __restrict__ ve2,
        float* __restrict__ V1, float* __restrict__ V2) {
    int i = blockIdx.x * 256 + threadIdx.x;
    float la = La[i];
    V1[i] = powf(la, ve[0]);
    float b = 2.0f * (la - 1e-8f) - 1.0f;
    V2[i] = powf(b * b + 1.0f, ve2[0]);
}

// U (f32 row-major) -> Ubf (bf16 row-major) + Utbf (bf16 transpose, row-major).
// Fully coalesced reads and (full-line) writes; LDS-tiled transpose.
__global__ __launch_bounds__(256) void convert_u(const float* __restrict__ U,
        unsigned short* __restrict__ Ubf, unsigned short* __restrict__ Utbf) {
    __shared__ unsigned short t[64][72];
    int i0 = blockIdx.y * 64, j0 = blockIdx.x * 64;
    int tid = threadIdx.x;
    int r = tid >> 3, c8 = (tid & 7) * 8;
#pragma unroll
    for (int it = 0; it < 2; ++it) {
        int row = it * 32 + r;
        const float* p = U + (size_t)(i0 + row) * NN + j0 + c8;
        f32x4 a = *(const f32x4*)p;
        f32x4 b = *(const f32x4*)(p + 4);
        u16x8 o;
#pragma unroll
        for (int q = 0; q < 4; ++q) { o[q] = f2bf(a[q]); o[4 + q] = f2bf(b[q]); }
        *(u16x8*)(Ubf + (size_t)(i0 + row) * NN + j0 + c8) = o;
#pragma unroll
        for (int q = 0; q < 8; ++q) t[row][c8 + q] = o[q];
    }
    __syncthreads();
#pragma unroll
    for (int it = 0; it < 2; ++it) {
        int row = it * 32 + r;   // row within j-tile -> output row j0+row
        u16x8 o;
#pragma unroll
        for (int q = 0; q < 8; ++q) o[q] = t[c8 + q][row];
        *(u16x8*)(Utbf + (size_t)(j0 + row) * NN + i0 + c8) = o;
    }
}

// ---------------------------------------------------------------------------
// FB frag layout (small matrix M[8192][64]):
//   FB[((b*4+nf)*64 + l)*8 + s] = M[32b + 8(l>>4) + s][16nf + (l&15)]
// gemm_n: C[i][j] = sum_k A[i][k] * S[k][j];  A = bf16 row-major (Ubf or Utbf),
// B = S via FB (contiguous 1KB wave loads, L2-resident).
// Output P[sk][i][j] f32 partials. No LDS, no barriers, reg ping-pong.
// ---------------------------------------------------------------------------
__global__ __launch_bounds__(256, 6) void gemm_n(const unsigned short* __restrict__ Ab,
        const unsigned short* __restrict__ FB, float* __restrict__ P) {
    const int tid = threadIdx.x;
    const int w = tid >> 6, l = tid & 63;
    const int lm = l & 15, g = l >> 4;
    const int i0 = blockIdx.x * 64;
    const int kbase = blockIdx.y * KSL;
    const int kb0 = kbase >> 5;
    const int m0 = i0 + w * 16;
    const unsigned short* ap = Ab + (size_t)(m0 + lm) * NN + kbase + 8 * g;
    const unsigned short* fbL = FB + (size_t)l * 8;

    f32x4 acc[4];
#pragma unroll
    for (int nf = 0; nf < 4; ++nf) acc[nf] = (f32x4)0.f;
    bf16x8 a0[2], a1[2];

#define NA(r, c)                                                               \
    do {                                                                       \
        const unsigned short* p_ = ap + 64 * (c);                              \
        r[0] = *(const bf16x8*)(p_);                                           \
        r[1] = *(const bf16x8*)(p_ + 32);                                      \
    } while (0)
#define NB(bf, c)                                                              \
    do {                                                                       \
        _Pragma("unroll")                                                      \
        for (int sp_ = 0; sp_ < 2; ++sp_)                                      \
            _Pragma("unroll")                                                  \
            for (int nf_ = 0; nf_ < 4; ++nf_)                                  \
                bf[sp_ * 4 + nf_] = *(const bf16x8*)(fbL +                     \
                    ((size_t)((kb0 + 2 * (c) + sp_) * 4 + nf_)) * 512);        \
    } while (0)
#define NCOMP(r, bf)                                                           \
    do {                                                                       \
        _Pragma("unroll")                                                      \
        for (int sp_ = 0; sp_ < 2; ++sp_)                                      \
            _Pragma("unroll")                                                  \
            for (int nf_ = 0; nf_ < 4; ++nf_)                                  \
                acc[nf_] = __builtin_amdgcn_mfma_f32_16x16x32_bf16(            \
                    r[sp_], bf[sp_ * 4 + nf_], acc[nf_], 0, 0, 0);             \
    } while (0)

    NA(a0, 0);
#pragma unroll
    for (int c = 0; c < NC; c += 2) {
        {
            bf16x8 bf[8];
            NB(bf, c);
            NA(a1, c + 1);
            NCOMP(a0, bf);
        }
        {
            bf16x8 bf[8];
            NB(bf, c + 1);
            if (c + 2 < NC) NA(a0, c + 2);
            NCOMP(a1, bf);
        }
    }
#undef NA
#undef NB
#undef NCOMP
    float* Pp = P + (size_t)blockIdx.y * NN * 64;
#pragma unroll
    for (int nf = 0; nf < 4; ++nf)
#pragma unroll
        for (int r = 0; r < 4; ++r)
            Pp[(size_t)(m0 + 4 * g + r) * 64 + nf * 16 + lm] = acc[nf][r];
}

// reduce_t: FB = frag( rowscale(V) * sum_sk M[sk][i][j] ), M [nsk][NN][64].
__global__ __launch_bounds__(256) void reduce_t(const float* __restrict__ M, int nsk,
        const float* __restrict__ V, unsigned short* __restrict__ FB) {
    __shared__ float T[32][65];
    int b = blockIdx.x;
    int i0 = b * 32;
    int tid = threadIdx.x;
    int il = tid >> 3, jq = (tid & 7) * 8;
    f32x4 s0 = (f32x4)0.f, s1 = (f32x4)0.f;
    for (int k = 0; k < nsk; ++k) {
        const float* p = M + ((size_t)k * NN + i0 + il) * 64 + jq;
        s0 += *(const f32x4*)p;
        s1 += *(const f32x4*)(p + 4);
    }
    float sc = V ? V[i0 + il] : 1.0f;
#pragma unroll
    for (int c = 0; c < 4; ++c) {
        T[il][jq + c] = s0[c] * sc;
        T[il][jq + 4 + c] = s1[c] * sc;
    }
    __syncthreads();
    int nf = tid >> 6, l = tid & 63, g = l >> 4, lm = l & 15;
    u16x8 o;
#pragma unroll
    for (int s = 0; s < 8; ++s) o[s] = f2bf(T[8 * g + s][16 * nf + lm]);
    *(u16x8*)(FB + ((size_t)(b * 4 + nf) * 64 + l) * 8) = o;
}

// Z2 = sum of partials; hidden = Z2 @ Ww^T + Wb; also per-block BN partial sums.
__global__ __launch_bounds__(256) void reduce_linear(const float* __restrict__ P,
        const float* __restrict__ Ww, const float* __restrict__ Wb,
        float* __restrict__ hidden, float* __restrict__ bsum, float* __restrict__ bsq) {
    __shared__ float z[32][65];
    __shared__ float w[64][65];
    __shared__ float hl[32][65];
    int i0 = blockIdx.x * 32;
    int tid = threadIdx.x;
    for (int e = tid * 4; e < 4096; e += 1024) {
        f32x4 v = *(const f32x4*)(Ww + e);
        int h = e >> 6, c = e & 63;
#pragma unroll
        for (int q = 0; q < 4; ++q) w[h][c + q] = v[q];
    }
    int r = tid >> 3, c8 = (tid & 7) * 8;
    f32x4 a0 = (f32x4)0.f, a1 = (f32x4)0.f;
    for (int k = 0; k < SK; ++k) {
        const float* p = P + ((size_t)k * NN + i0 + r) * 64 + c8;
        a0 += *(const f32x4*)p;
        a1 += *(const f32x4*)(p + 4);
    }
#pragma unroll
    for (int q = 0; q < 4; ++q) { z[r][c8 + q] = a0[q]; z[r][c8 + 4 + q] = a1[q]; }
    __syncthreads();
    int h8 = (tid & 7) * 8;
#pragma unroll
    for (int hh = 0; hh < 8; ++hh) {
        int h = h8 + hh;
        float s = Wb[h];
        for (int c = 0; c < 64; ++c) s += z[r][c] * w[h][c];
        hidden[(size_t)(i0 + r) * 64 + h] = s;
        hl[r][h] = s;
    }
    __syncthreads();
    if (tid < 64) {
        float s = 0.f, q2 = 0.f;
#pragma unroll
        for (int rr = 0; rr < 32; ++rr) {
            float v = hl[rr][tid];
            s += v; q2 += v * v;
        }
        bsum[blockIdx.x * 64 + tid] = s;
        bsq[blockIdx.x * 64 + tid] = q2;
    }
}

__global__ __launch_bounds__(64) void bn_stats(const float* __restrict__ bsum,
        const float* __restrict__ bsq, const float* __restrict__ gamma,
        const float* __restrict__ beta, float* __restrict__ bnc) {
    int h = threadIdx.x;
    float s = 0.f, q = 0.f;
    for (int b = 0; b < 256; ++b) { s += bsum[b * 64 + h]; q += bsq[b * 64 + h]; }
    float mean = s / 8192.0f;
    float var = q / 8192.0f - mean * mean;
    float inv = rsqrtf(var + 1e-5f);
    float sc = gamma[h] * inv;
    bnc[h] = sc;
    bnc[64 + h] = beta[h] - mean * sc;
}

__global__ __launch_bounds__(256) void head(const float* __restrict__ hidden,
        const float* __restrict__ bnc, const float* __restrict__ Mw,
        const float* __restrict__ Mb, float* __restrict__ out0) {
    __shared__ float a[32][65];
    __shared__ float w[32][65];
    __shared__ float o[32][33];
    __shared__ float rowm[32];
    int i0 = blockIdx.x * 32;
    int tid = threadIdx.x;
    for (int e = tid * 4; e < 2048; e += 1024) {
        f32x4 v = *(const f32x4*)(Mw + e);
        int oo = e >> 6, c = e & 63;
#pragma unroll
        for (int q = 0; q < 4; ++q) w[oo][c + q] = v[q];
    }
    int r = tid >> 3, h8 = (tid & 7) * 8;
    const float* hp = hidden + (size_t)(i0 + r) * 64 + h8;
#pragma unroll
    for (int q = 0; q < 8; ++q) {
        int h = h8 + q;
        float v = hp[q] * bnc[h] + bnc[64 + h];
        a[r][h] = fmaxf(v, 0.f);
    }
    __syncthreads();
    int o4 = (tid & 7) * 4;
#pragma unroll
    for (int q = 0; q < 4; ++q) {
        int oo = o4 + q;
        float s = Mb[oo];
        for (int c = 0; c < 64; ++c) s += a[r][c] * w[oo][c];
        o[r][oo] = s;
    }
    __syncthreads();
    if (tid < 32) {
        float m = -3.0e38f;
#pragma unroll
        for (int c = 0; c < 32; ++c) m = fmaxf(m, o[tid][c]);
        float se = 0.f;
#pragma unroll
        for (int c = 0; c < 32; ++c) se += expf(o[tid][c] - m);
        rowm[tid] = m + logf(se);
    }
    __syncthreads();
    f32x4 v;
#pragma unroll
    for (int q = 0; q < 4; ++q) v[q] = o[r][o4 + q] - rowm[r];
    *(f32x4*)(out0 + (size_t)(i0 + r) * 32 + o4) = v;
}

extern "C" void kernel_launch(void* const* d_in, const int* in_sizes, int n_in,
                              void* d_out, int out_size, void* d_ws, size_t ws_size,
                              hipStream_t stream) {
    const float* X   = (const float*)d_in[0];
    const float* La  = (const float*)d_in[1];
    const float* U   = (const float*)d_in[2];
    const float* ve  = (const float*)d_in[3];
    const float* ve2 = (const float*)d_in[4];
    const float* Ww  = (const float*)d_in[5];
    const float* Wb  = (const float*)d_in[6];
    const float* gam = (const float*)d_in[7];
    const float* bet = (const float*)d_in[8];
    const float* Mw  = (const float*)d_in[9];
    const float* Mb  = (const float*)d_in[10];
    float* out0 = (float*)d_out;
    float* hidden = (float*)d_out + (size_t)NN * 32;   // output 1 region

    char* ws = (char*)d_ws;
    float* V1   = (float*)ws;                             // 32 KB
    float* V2   = (float*)(ws + 32768);                   // 32 KB
    float* bsum = (float*)(ws + 65536);                   // 64 KB
    float* bsq  = (float*)(ws + 131072);                  // 64 KB
    float* bnc  = (float*)(ws + 196608);                  // 512 B
    unsigned short* FB = (unsigned short*)(ws + 262144);  // 1 MB frag-major bf16
    float* P    = (float*)(ws + (2u << 20));              // 32 MB [SK][NN][64]
    unsigned short* Ubf  = (unsigned short*)(ws + (64u << 20));   // 128 MB
    unsigned short* Utbf = (unsigned short*)(ws + (192u << 20));  // 128 MB

    prep_v<<<32, 256, 0, stream>>>(La, ve, ve2, V1, V2);
    convert_u<<<dim3(128, 128), 256, 0, stream>>>(U, Ubf, Utbf);
    // FB = frag(X)
    reduce_t<<<256, 256, 0, stream>>>(X, 1, nullptr, FB);
    // T1 = U^T @ X   (A = Utbf)
    gemm_n<<<dim3(NN / 64, SK), 256, 0, stream>>>(Utbf, FB, P);
    // FB = frag(V1 .* T1)
    reduce_t<<<256, 256, 0, stream>>>(P, SK, V1, FB);
    // Z1 = U @ S1    (A = Ubf)
    gemm_n<<<dim3(NN / 64, SK), 256, 0, stream>>>(Ubf, FB, P);
    // FB = frag(Z1)
    reduce_t<<<256, 256, 0, stream>>>(P, SK, nullptr, FB);
    // T2 = U^T @ Z1  (A = Utbf)
    gemm_n<<<dim3(NN / 64, SK), 256, 0, stream>>>(Utbf, FB, P);
    // FB = frag(V2 .* T2)
    reduce_t<<<256, 256, 0, stream>>>(P, SK, V2, FB);
    // Z2 = U @ S2    (A = Ubf)
    gemm_n<<<dim3(NN / 64, SK), 256, 0, stream>>>(Ubf, FB, P);
    // hidden = Z2 @ Ww^T + Wb  (+ BN partial stats)
    reduce_linear<<<256, 256, 0, stream>>>(P, Ww, Wb, hidden, bsum, bsq);
    bn_stats<<<1, 64, 0, stream>>>(bsum, bsq, gam, bet, bnc);
    head<<<256, 256, 0, stream>>>(hidden, bnc, Mw, Mb, out0);
}

// Round 9
// 311.416 us; speedup vs baseline: 1.1569x; 1.1569x over previous
//
#include <hip/hip_runtime.h>
#include <hip/hip_bf16.h>

typedef __attribute__((ext_vector_type(4))) float f32x4;
typedef __attribute__((ext_vector_type(8))) short bf16x8;
typedef __attribute__((ext_vector_type(8))) unsigned short u16x8;
typedef __attribute__((ext_vector_type(4))) unsigned short u16x4;

#define NN 8192
#define SK 8
#define KSL (NN / SK)      // 1024 k per WG

__device__ __forceinline__ unsigned short f2bf(float f) {
    unsigned int u = __float_as_uint(f);
    u += 0x7fffu + ((u >> 16) & 1u);
    return (unsigned short)(u >> 16);
}

__global__ __launch_bounds__(256) void prep_v(const float* __restrict__ La,
        const float* __restrict__ ve, const float* __restrict__ ve2,
        float* __restrict__ V1, float* __restrict__ V2) {
    int i = blockIdx.x * 256 + threadIdx.x;
    float la = La[i];
    V1[i] = powf(la, ve[0]);
    float b = 2.0f * (la - 1e-8f) - 1.0f;
    V2[i] = powf(b * b + 1.0f, ve2[0]);
}

// ---------------------------------------------------------------------------
// FB frag layout (small matrix M[8192][64]):
//   FB[((b*4+nf)*64 + l)*8 + s] = M[32b + 8(l>>4) + s][16nf + (l&15)]
// ---------------------------------------------------------------------------

// gemm_tn: Pt[m][n] = sum_k M[k][m] * U[k][n]   (= (U^T M)^T)
// A = M via FB (L2-resident), B = U streamed ROW-major (full 128B lines),
// staged per 32x64 tile into wave-private LDS (no barriers).
// BF=0: U f32, converts and emits Ubf (each (k,n) exactly once). BF=1: U bf16.
// Output Pt[sk][64][NN] partials.
template<int BF>
__global__ __launch_bounds__(256, 4) void gemm_tn(const void* __restrict__ Usrc,
        const unsigned short* __restrict__ FB, float* __restrict__ Pt,
        unsigned short* __restrict__ Uemit) {
    __shared__ unsigned short lds[4][32 * 72];   // 4.6 KB per wave, stride 72
    const int tid = threadIdx.x;
    const int w = tid >> 6, l = tid & 63;
    const int lm = l & 15, g = l >> 4;
    const int n0 = blockIdx.x * 64;
    const int kbase = blockIdx.y * KSL;
    const int kb0 = kbase >> 5;
    unsigned short* T = lds[w];

    f32x4 acc[4];
#pragma unroll
    for (int mf = 0; mf < 4; ++mf) acc[mf] = (f32x4)0.f;
    const unsigned short* fbL = FB + (size_t)l * 8;

#pragma unroll 2
    for (int c = 0; c < KSL / 32; ++c) {
        const int k0 = kbase + 32 * c;
        if (!BF) {
            // 8 instrs: 4 rows x (16 lanes x 16B = 256B) each -> full lines
            const float* up = (const float*)Usrc +
                (size_t)(k0 + (l >> 4)) * NN + n0 + lm * 4;
#pragma unroll
            for (int i = 0; i < 8; ++i) {
                f32x4 v = *(const f32x4*)(up + (size_t)(4 * i) * NN);
                u16x4 h;
#pragma unroll
                for (int q = 0; q < 4; ++q) h[q] = f2bf(v[q]);
                int row = 4 * i + (l >> 4);
                *(u16x4*)(T + row * 72 + lm * 4) = h;
                *(u16x4*)(Uemit + (size_t)(k0 + row) * NN + n0 + lm * 4) = h;
            }
        } else {
            // 4 instrs: 8 rows x 128B full lines each
            const unsigned short* up = (const unsigned short*)Usrc +
                (size_t)(k0 + (l >> 3)) * NN + n0 + (l & 7) * 8;
#pragma unroll
            for (int i = 0; i < 4; ++i) {
                u16x8 v = *(const u16x8*)(up + (size_t)(8 * i) * NN);
                int row = 8 * i + (l >> 3);
                *(u16x8*)(T + row * 72 + (l & 7) * 8) = v;
            }
        }
        // A-fragments from FB (independent of staging)
        bf16x8 af[4];
#pragma unroll
        for (int nf = 0; nf < 4; ++nf)
            af[nf] = *(const bf16x8*)(fbL + (size_t)((kb0 + c) * 4 + nf) * 512);
        // B-fragment: this wave's 16-col slice, k = 8g+s
        bf16x8 bfr;
#pragma unroll
        for (int s = 0; s < 8; ++s)
            bfr[s] = (short)T[(8 * g + s) * 72 + 16 * w + lm];
#pragma unroll
        for (int mf = 0; mf < 4; ++mf)
            acc[mf] = __builtin_amdgcn_mfma_f32_16x16x32_bf16(
                af[mf], bfr, acc[mf], 0, 0, 0);
    }
    float* Pp = Pt + (size_t)blockIdx.y * 64 * NN;
#pragma unroll
    for (int mf = 0; mf < 4; ++mf)
#pragma unroll
        for (int r = 0; r < 4; ++r)
            Pp[(size_t)(16 * mf + 4 * g + r) * NN + n0 + 16 * w + lm] = acc[mf][r];
}

// gemm_n: C[i][j] = sum_k Ubf[i][k] * S[k][j]; A = Ubf rows (bf16, direct),
// B = S via FB. Output P[sk][i][j] f32 partials. No LDS, no barriers.
__global__ __launch_bounds__(256, 4) void gemm_n(const unsigned short* __restrict__ Ab,
        const unsigned short* __restrict__ FB, float* __restrict__ P) {
    const int tid = threadIdx.x;
    const int w = tid >> 6, l = tid & 63;
    const int lm = l & 15, g = l >> 4;
    const int i0 = blockIdx.x * 64;
    const int kbase = blockIdx.y * KSL;
    const int kb0 = kbase >> 5;
    const int m0 = i0 + w * 16;
    const unsigned short* ap = Ab + (size_t)(m0 + lm) * NN + kbase + 8 * g;
    const unsigned short* fbL = FB + (size_t)l * 8;

    f32x4 acc[4];
#pragma unroll
    for (int nf = 0; nf < 4; ++nf) acc[nf] = (f32x4)0.f;
    bf16x8 a0[2], a1[2];

#define NA(r, c)                                                               \
    do {                                                                       \
        const unsigned short* p_ = ap + 64 * (c);                              \
        r[0] = *(const bf16x8*)(p_);                                           \
        r[1] = *(const bf16x8*)(p_ + 32);                                      \
    } while (0)
#define NB(bf, c)                                                              \
    do {                                                                       \
        _Pragma("unroll")                                                      \
        for (int sp_ = 0; sp_ < 2; ++sp_)                                      \
            _Pragma("unroll")                                                  \
            for (int nf_ = 0; nf_ < 4; ++nf_)                                  \
                bf[sp_ * 4 + nf_] = *(const bf16x8*)(fbL +                     \
                    ((size_t)((kb0 + 2 * (c) + sp_) * 4 + nf_)) * 512);        \
    } while (0)
#define NCOMP(r, bf)                                                           \
    do {                                                                       \
        _Pragma("unroll")                                                      \
        for (int sp_ = 0; sp_ < 2; ++sp_)                                      \
            _Pragma("unroll")                                                  \
            for (int nf_ = 0; nf_ < 4; ++nf_)                                  \
                acc[nf_] = __builtin_amdgcn_mfma_f32_16x16x32_bf16(            \
                    r[sp_], bf[sp_ * 4 + nf_], acc[nf_], 0, 0, 0);             \
    } while (0)

    NA(a0, 0);
#pragma unroll
    for (int c = 0; c < KSL / 64; c += 2) {
        {
            bf16x8 bf[8];
            NB(bf, c);
            NA(a1, c + 1);
            NCOMP(a0, bf);
        }
        {
            bf16x8 bf[8];
            NB(bf, c + 1);
            if (c + 2 < KSL / 64) NA(a0, c + 2);
            NCOMP(a1, bf);
        }
    }
#undef NA
#undef NB
#undef NCOMP
    float* Pp = P + (size_t)blockIdx.y * NN * 64;
#pragma unroll
    for (int nf = 0; nf < 4; ++nf)
#pragma unroll
        for (int r = 0; r < 4; ++r)
            Pp[(size_t)(m0 + 4 * g + r) * 64 + nf * 16 + lm] = acc[nf][r];
}

// reduce2: FB = frag( colscale(V) * sum_sk Pt[sk][ch][i] ), Pt [SK][64][NN]
__global__ __launch_bounds__(256) void reduce2(const float* __restrict__ Pt,
        const float* __restrict__ V, unsigned short* __restrict__ FB) {
    int b = blockIdx.x;
    int t = threadIdx.x;
    int nf = t >> 6, l = t & 63, lm = l & 15, g = l >> 4;
    int ch = 16 * nf + lm;
    int ib = 32 * b + 8 * g;
    f32x4 s0 = (f32x4)0.f, s1 = (f32x4)0.f;
#pragma unroll
    for (int sk = 0; sk < SK; ++sk) {
        const float* p = Pt + (size_t)(sk * 64 + ch) * NN + ib;
        s0 += *(const f32x4*)p;
        s1 += *(const f32x4*)(p + 4);
    }
    f32x4 v0 = *(const f32x4*)(V + ib);
    f32x4 v1 = *(const f32x4*)(V + ib + 4);
    u16x8 o;
#pragma unroll
    for (int c = 0; c < 4; ++c) {
        o[c]     = f2bf(s0[c] * v0[c]);
        o[4 + c] = f2bf(s1[c] * v1[c]);
    }
    *(u16x8*)(FB + ((size_t)(b * 4 + nf) * 64 + l) * 8) = o;
}

// reduce_t: FB = frag( sum_sk M[sk][i][j] ), M [nsk][NN][64] row-major.
__global__ __launch_bounds__(256) void reduce_t(const float* __restrict__ M, int nsk,
        unsigned short* __restrict__ FB) {
    __shared__ float T[32][65];
    int b = blockIdx.x;
    int i0 = b * 32;
    int tid = threadIdx.x;
    int il = tid >> 3, jq = (tid & 7) * 8;
    f32x4 s0 = (f32x4)0.f, s1 = (f32x4)0.f;
    for (int k = 0; k < nsk; ++k) {
        const float* p = M + ((size_t)k * NN + i0 + il) * 64 + jq;
        s0 += *(const f32x4*)p;
        s1 += *(const f32x4*)(p + 4);
    }
#pragma unroll
    for (int c = 0; c < 4; ++c) {
        T[il][jq + c] = s0[c];
        T[il][jq + 4 + c] = s1[c];
    }
    __syncthreads();
    int nf = tid >> 6, l = tid & 63, g = l >> 4, lm = l & 15;
    u16x8 o;
#pragma unroll
    for (int s = 0; s < 8; ++s) o[s] = f2bf(T[8 * g + s][16 * nf + lm]);
    *(u16x8*)(FB + ((size_t)(b * 4 + nf) * 64 + l) * 8) = o;
}

// Z2 = sum of partials; hidden = Z2 @ Ww^T + Wb; also per-block BN partial sums.
__global__ __launch_bounds__(256) void reduce_linear(const float* __restrict__ P,
        const float* __restrict__ Ww, const float* __restrict__ Wb,
        float* __restrict__ hidden, float* __restrict__ bsum, float* __restrict__ bsq) {
    __shared__ float z[32][65];
    __shared__ float w[64][65];
    __shared__ float hl[32][65];
    int i0 = blockIdx.x * 32;
    int tid = threadIdx.x;
    for (int e = tid * 4; e < 4096; e += 1024) {
        f32x4 v = *(const f32x4*)(Ww + e);
        int h = e >> 6, c = e & 63;
#pragma unroll
        for (int q = 0; q < 4; ++q) w[h][c + q] = v[q];
    }
    int r = tid >> 3, c8 = (tid & 7) * 8;
    f32x4 a0 = (f32x4)0.f, a1 = (f32x4)0.f;
    for (int k = 0; k < SK; ++k) {
        const float* p = P + ((size_t)k * NN + i0 + r) * 64 + c8;
        a0 += *(const f32x4*)p;
        a1 += *(const f32x4*)(p + 4);
    }
#pragma unroll
    for (int q = 0; q < 4; ++q) { z[r][c8 + q] = a0[q]; z[r][c8 + 4 + q] = a1[q]; }
    __syncthreads();
    int h8 = (tid & 7) * 8;
#pragma unroll
    for (int hh = 0; hh < 8; ++hh) {
        int h = h8 + hh;
        float s = Wb[h];
        for (int c = 0; c < 64; ++c) s += z[r][c] * w[h][c];
        hidden[(size_t)(i0 + r) * 64 + h] = s;
        hl[r][h] = s;
    }
    __syncthreads();
    if (tid < 64) {
        float s = 0.f, q2 = 0.f;
#pragma unroll
        for (int rr = 0; rr < 32; ++rr) {
            float v = hl[rr][tid];
            s += v; q2 += v * v;
        }
        bsum[blockIdx.x * 64 + tid] = s;
        bsq[blockIdx.x * 64 + tid] = q2;
    }
}

__global__ __launch_bounds__(64) void bn_stats(const float* __restrict__ bsum,
        const float* __restrict__ bsq, const float* __restrict__ gamma,
        const float* __restrict__ beta, float* __restrict__ bnc) {
    int h = threadIdx.x;
    float s = 0.f, q = 0.f;
    for (int b = 0; b < 256; ++b) { s += bsum[b * 64 + h]; q += bsq[b * 64 + h]; }
    float mean = s / 8192.0f;
    float var = q / 8192.0f - mean * mean;
    float inv = rsqrtf(var + 1e-5f);
    float sc = gamma[h] * inv;
    bnc[h] = sc;
    bnc[64 + h] = beta[h] - mean * sc;
}

__global__ __launch_bounds__(256) void head(const float* __restrict__ hidden,
        const float* __restrict__ bnc, const float* __restrict__ Mw,
        const float* __restrict__ Mb, float* __restrict__ out0) {
    __shared__ float a[32][65];
    __shared__ float w[32][65];
    __shared__ float o[32][33];
    __shared__ float rowm[32];
    int i0 = blockIdx.x * 32;
    int tid = threadIdx.x;
    for (int e = tid * 4; e < 2048; e += 1024) {
        f32x4 v = *(const f32x4*)(Mw + e);
        int oo = e >> 6, c = e & 63;
#pragma unroll
        for (int q = 0; q < 4; ++q) w[oo][c + q] = v[q];
    }
    int r = tid >> 3, h8 = (tid & 7) * 8;
    const float* hp = hidden + (size_t)(i0 + r) * 64 + h8;
#pragma unroll
    for (int q = 0; q < 8; ++q) {
        int h = h8 + q;
        float v = hp[q] * bnc[h] + bnc[64 + h];
        a[r][h] = fmaxf(v, 0.f);
    }
    __syncthreads();
    int o4 = (tid & 7) * 4;
#pragma unroll
    for (int q = 0; q < 4; ++q) {
        int oo = o4 + q;
        float s = Mb[oo];
        for (int c = 0; c < 64; ++c) s += a[r][c] * w[oo][c];
        o[r][oo] = s;
    }
    __syncthreads();
    if (tid < 32) {
        float m = -3.0e38f;
#pragma unroll
        for (int c = 0; c < 32; ++c) m = fmaxf(m, o[tid][c]);
        float se = 0.f;
#pragma unroll
        for (int c = 0; c < 32; ++c) se += expf(o[tid][c] - m);
        rowm[tid] = m + logf(se);
    }
    __syncthreads();
    f32x4 v;
#pragma unroll
    for (int q = 0; q < 4; ++q) v[q] = o[r][o4 + q] - rowm[r];
    *(f32x4*)(out0 + (size_t)(i0 + r) * 32 + o4) = v;
}

extern "C" void kernel_launch(void* const* d_in, const int* in_sizes, int n_in,
                              void* d_out, int out_size, void* d_ws, size_t ws_size,
                              hipStream_t stream) {
    const float* X   = (const float*)d_in[0];
    const float* La  = (const float*)d_in[1];
    const float* U   = (const float*)d_in[2];
    const float* ve  = (const float*)d_in[3];
    const float* ve2 = (const float*)d_in[4];
    const float* Ww  = (const float*)d_in[5];
    const float* Wb  = (const float*)d_in[6];
    const float* gam = (const float*)d_in[7];
    const float* bet = (const float*)d_in[8];
    const float* Mw  = (const float*)d_in[9];
    const float* Mb  = (const float*)d_in[10];
    float* out0 = (float*)d_out;
    float* hidden = (float*)d_out + (size_t)NN * 32;   // output 1 region

    char* ws = (char*)d_ws;
    float* V1   = (float*)ws;                             // 32 KB
    float* V2   = (float*)(ws + 32768);                   // 32 KB
    float* bsum = (float*)(ws + 65536);                   // 64 KB
    float* bsq  = (float*)(ws + 131072);                  // 64 KB
    float* bnc  = (float*)(ws + 196608);                  // 512 B
    unsigned short* FB = (unsigned short*)(ws + 262144);  // 1 MB frag-major bf16
    float* P    = (float*)(ws + (2u << 20));              // 16 MB [SK][NN][64]
    float* Pt   = (float*)(ws + (20u << 20));             // 16 MB [SK][64][NN]
    unsigned short* Ubf = (unsigned short*)(ws + (64u << 20));  // 128 MB bf16 U

    prep_v<<<32, 256, 0, stream>>>(La, ve, ve2, V1, V2);
    // FB = frag(X)
    reduce_t<<<256, 256, 0, stream>>>(X, 1, FB);
    // T1^T partials = X^T @ U   (U f32, row-major streams; emits Ubf)
    gemm_tn<0><<<dim3(NN / 64, SK), 256, 0, stream>>>(U, FB, Pt, Ubf);
    // FB = frag(V1 .* T1)
    reduce2<<<256, 256, 0, stream>>>(Pt, V1, FB);
    // Z1 = U @ S1
    gemm_n<<<dim3(NN / 64, SK), 256, 0, stream>>>(Ubf, FB, P);
    // FB = frag(Z1)
    reduce_t<<<256, 256, 0, stream>>>(P, SK, FB);
    // T2^T partials = Z1^T @ U  (Ubf row-major streams)
    gemm_tn<1><<<dim3(NN / 64, SK), 256, 0, stream>>>(Ubf, FB, Pt, nullptr);
    // FB = frag(V2 .* T2)
    reduce2<<<256, 256, 0, stream>>>(Pt, V2, FB);
    // Z2 = U @ S2
    gemm_n<<<dim3(NN / 64, SK), 256, 0, stream>>>(Ubf, FB, P);
    // hidden = Z2 @ Ww^T + Wb  (+ BN partial stats)
    reduce_linear<<<256, 256, 0, stream>>>(P, Ww, Wb, hidden, bsum, bsq);
    bn_stats<<<1, 64, 0, stream>>>(bsum, bsq, gam, bet, bnc);
    head<<<256, 256, 0, stream>>>(hidden, bnc, Mw, Mb, out0);
}

// Round 10
// 252.029 us; speedup vs baseline: 1.4295x; 1.2356x over previous
//
#include <hip/hip_runtime.h>
#include <hip/hip_bf16.h>

typedef __attribute__((ext_vector_type(4))) float f32x4;
typedef __attribute__((ext_vector_type(8))) short bf16x8;
typedef __attribute__((ext_vector_type(8))) unsigned short u16x8;

#define NN 8192
#define SK 8
#define KSL (NN / SK)      // 1024 k per WG
#define NT (KSL / 64)      // 16 tiles of 64 k

__device__ __forceinline__ unsigned short f2bf(float f) {
    unsigned int u = __float_as_uint(f);
    u += 0x7fffu + ((u >> 16) & 1u);
    return (unsigned short)(u >> 16);
}

__device__ __forceinline__ void gload16(const float* g, float* l) {
    __builtin_amdgcn_global_load_lds(
        (const __attribute__((address_space(1))) unsigned int*)g,
        (__attribute__((address_space(3))) unsigned int*)l, 16, 0, 0);
}

__global__ __launch_bounds__(256) void prep_v(const float* __restrict__ La,
        const float* __restrict__ ve, const float* __restrict__ ve2,
        float* __restrict__ V1, float* __restrict__ V2) {
    int i = blockIdx.x * 256 + threadIdx.x;
    float la = La[i];
    V1[i] = powf(la, ve[0]);
    float b = 2.0f * (la - 1e-8f) - 1.0f;
    V2[i] = powf(b * b + 1.0f, ve2[0]);
}

// ---------------------------------------------------------------------------
// FB frag layout (small matrix M[8192][64]):
//   FB[((b*4+nf)*64 + l)*8 + s] = M[32b + 8(l>>4) + s][16nf + (l&15)]
//
// spec_pass<0> (n): C[i][j]  = sum_k U[i][k] * S[k][j]; out P[sk][NN][64]
// spec_pass<1> (t): C'[m][n] = sum_k M[k][m] * U[k][n]; out Pt[sk][64][NN]
// U staged 64x64 f32 tiles via global_load_lds (dbuf, source-XOR-swizzled,
// LDS linear); FB prefetched one tile ahead into regs. m97-style 2 barriers
// per tile; compute phase has no vmcnt waits.
// ---------------------------------------------------------------------------
template<int TM>
__global__ __launch_bounds__(256, 4) void spec_pass(const float* __restrict__ U,
        const unsigned short* __restrict__ FB, float* __restrict__ Pout) {
    __shared__ float tile[2][4096];          // 2 x 16 KB
    const int tid = threadIdx.x;
    const int w = tid >> 6, l = tid & 63;
    const int lm = l & 15, g = l >> 4;
    const int x0 = blockIdx.x * 64;          // n: row-block; t: col-block
    const int kbase = blockIdx.y * KSL;
    const int kb0 = kbase >> 5;
    const unsigned short* fbL = FB + (size_t)l * 8;

    f32x4 acc[4];
#pragma unroll
    for (int f = 0; f < 4; ++f) acc[f] = (f32x4)0.f;

#define STAGE(B, CT)                                                           \
    do {                                                                       \
        _Pragma("unroll")                                                      \
        for (int q_ = 0; q_ < 4; ++q_) {                                       \
            const int cc_ = 4 * w + q_;                                        \
            const int row_ = 4 * cc_ + (l >> 4);                               \
            const int su_ = (l & 15) ^ (row_ & 7);                             \
            const float* gp_ = U +                                             \
                (size_t)(TM ? (kbase + (CT) * 64 + row_) : (x0 + row_)) * NN + \
                (TM ? x0 : (kbase + (CT) * 64)) + su_ * 4;                     \
            gload16(gp_, &tile[B][cc_ * 256]);                                 \
        }                                                                      \
    } while (0)

#define LOADFB(R, CT)                                                          \
    do {                                                                       \
        _Pragma("unroll")                                                      \
        for (int sp_ = 0; sp_ < 2; ++sp_)                                      \
            _Pragma("unroll")                                                  \
            for (int f_ = 0; f_ < 4; ++f_)                                     \
                R[sp_][f_] = *(const bf16x8*)(fbL +                            \
                    ((size_t)((kb0 + 2 * (CT) + sp_) * 4 + f_)) * 512);        \
    } while (0)

#define COMPUTE(B, FBR)                                                        \
    do {                                                                       \
        _Pragma("unroll")                                                      \
        for (int sp_ = 0; sp_ < 2; ++sp_) {                                    \
            if (!TM) {                                                         \
                const float* rp_ = &tile[B][(16 * w + lm) * 64];               \
                const int m7_ = lm & 7;                                        \
                f32x4 p0_ = *(const f32x4*)(rp_ +                              \
                    (((8 * sp_ + 2 * g) ^ m7_) << 2));                         \
                f32x4 p1_ = *(const f32x4*)(rp_ +                              \
                    (((8 * sp_ + 2 * g + 1) ^ m7_) << 2));                     \
                bf16x8 afr_;                                                   \
                _Pragma("unroll")                                              \
                for (int j_ = 0; j_ < 4; ++j_) {                               \
                    afr_[j_]     = (short)f2bf(p0_[j_]);                       \
                    afr_[4 + j_] = (short)f2bf(p1_[j_]);                       \
                }                                                              \
                _Pragma("unroll")                                              \
                for (int f_ = 0; f_ < 4; ++f_)                                 \
                    acc[f_] = __builtin_amdgcn_mfma_f32_16x16x32_bf16(         \
                        afr_, FBR[sp_][f_], acc[f_], 0, 0, 0);                 \
            } else {                                                           \
                bf16x8 bfr_;                                                   \
                _Pragma("unroll")                                              \
                for (int s_ = 0; s_ < 8; ++s_)                                 \
                    bfr_[s_] = (short)f2bf(tile[B][                            \
                        (32 * sp_ + 8 * g + s_) * 64 +                         \
                        (((4 * w + (lm >> 2)) ^ s_) << 2) + (lm & 3)]);        \
                _Pragma("unroll")                                              \
                for (int f_ = 0; f_ < 4; ++f_)                                 \
                    acc[f_] = __builtin_amdgcn_mfma_f32_16x16x32_bf16(         \
                        FBR[sp_][f_], bfr_, acc[f_], 0, 0, 0);                 \
            }                                                                  \
        }                                                                      \
    } while (0)

    bf16x8 fbA[2][4], fbB[2][4];
    LOADFB(fbA, 0);
    STAGE(0, 0);
    __syncthreads();
#pragma unroll 1
    for (int c = 0; c < NT; c += 2) {
        if (c + 1 < NT) { LOADFB(fbB, c + 1); STAGE(1, c + 1); }
        COMPUTE(0, fbA);
        __syncthreads();
        if (c + 2 < NT) { LOADFB(fbA, c + 2); STAGE(0, c + 2); }
        COMPUTE(1, fbB);
        __syncthreads();
    }
#undef STAGE
#undef LOADFB
#undef COMPUTE

    if (!TM) {
        float* Pp = Pout + (size_t)blockIdx.y * NN * 64;
#pragma unroll
        for (int f = 0; f < 4; ++f)
#pragma unroll
            for (int r = 0; r < 4; ++r)
                Pp[(size_t)(x0 + 16 * w + 4 * g + r) * 64 + f * 16 + lm] = acc[f][r];
    } else {
        float* Pp = Pout + (size_t)blockIdx.y * 64 * NN;
#pragma unroll
        for (int f = 0; f < 4; ++f)
#pragma unroll
            for (int r = 0; r < 4; ++r)
                Pp[(size_t)(16 * f + 4 * g + r) * NN + x0 + 16 * w + lm] = acc[f][r];
    }
}

// reduce2: FB = frag( colscale(V) * sum_sk Pt[sk][ch][i] ), Pt [SK][64][NN]
__global__ __launch_bounds__(256) void reduce2(const float* __restrict__ Pt,
        const float* __restrict__ V, unsigned short* __restrict__ FB) {
    int b = blockIdx.x;
    int t = threadIdx.x;
    int nf = t >> 6, l = t & 63, lm = l & 15, g = l >> 4;
    int ch = 16 * nf + lm;
    int ib = 32 * b + 8 * g;
    f32x4 s0 = (f32x4)0.f, s1 = (f32x4)0.f;
#pragma unroll
    for (int sk = 0; sk < SK; ++sk) {
        const float* p = Pt + (size_t)(sk * 64 + ch) * NN + ib;
        s0 += *(const f32x4*)p;
        s1 += *(const f32x4*)(p + 4);
    }
    f32x4 v0 = *(const f32x4*)(V + ib);
    f32x4 v1 = *(const f32x4*)(V + ib + 4);
    u16x8 o;
#pragma unroll
    for (int c = 0; c < 4; ++c) {
        o[c]     = f2bf(s0[c] * v0[c]);
        o[4 + c] = f2bf(s1[c] * v1[c]);
    }
    *(u16x8*)(FB + ((size_t)(b * 4 + nf) * 64 + l) * 8) = o;
}

// reduce_t: FB = frag( sum_sk M[sk][i][j] ), M [nsk][NN][64] row-major.
__global__ __launch_bounds__(256) void reduce_t(const float* __restrict__ M, int nsk,
        unsigned short* __restrict__ FB) {
    __shared__ float T[32][65];
    int b = blockIdx.x;
    int i0 = b * 32;
    int tid = threadIdx.x;
    int il = tid >> 3, jq = (tid & 7) * 8;
    f32x4 s0 = (f32x4)0.f, s1 = (f32x4)0.f;
    for (int k = 0; k < nsk; ++k) {
        const float* p = M + ((size_t)k * NN + i0 + il) * 64 + jq;
        s0 += *(const f32x4*)p;
        s1 += *(const f32x4*)(p + 4);
    }
#pragma unroll
    for (int c = 0; c < 4; ++c) {
        T[il][jq + c] = s0[c];
        T[il][jq + 4 + c] = s1[c];
    }
    __syncthreads();
    int nf = tid >> 6, l = tid & 63, g = l >> 4, lm = l & 15;
    u16x8 o;
#pragma unroll
    for (int s = 0; s < 8; ++s) o[s] = f2bf(T[8 * g + s][16 * nf + lm]);
    *(u16x8*)(FB + ((size_t)(b * 4 + nf) * 64 + l) * 8) = o;
}

// Z2 = sum of partials; hidden = Z2 @ Ww^T + Wb; also per-block BN partial sums.
__global__ __launch_bounds__(256) void reduce_linear(const float* __restrict__ P,
        const float* __restrict__ Ww, const float* __restrict__ Wb,
        float* __restrict__ hidden, float* __restrict__ bsum, float* __restrict__ bsq) {
    __shared__ float z[32][65];
    __shared__ float w[64][65];
    __shared__ float hl[32][65];
    int i0 = blockIdx.x * 32;
    int tid = threadIdx.x;
    for (int e = tid * 4; e < 4096; e += 1024) {
        f32x4 v = *(const f32x4*)(Ww + e);
        int h = e >> 6, c = e & 63;
#pragma unroll
        for (int q = 0; q < 4; ++q) w[h][c + q] = v[q];
    }
    int r = tid >> 3, c8 = (tid & 7) * 8;
    f32x4 a0 = (f32x4)0.f, a1 = (f32x4)0.f;
    for (int k = 0; k < SK; ++k) {
        const float* p = P + ((size_t)k * NN + i0 + r) * 64 + c8;
        a0 += *(const f32x4*)p;
        a1 += *(const f32x4*)(p + 4);
    }
#pragma unroll
    for (int q = 0; q < 4; ++q) { z[r][c8 + q] = a0[q]; z[r][c8 + 4 + q] = a1[q]; }
    __syncthreads();
    int h8 = (tid & 7) * 8;
#pragma unroll
    for (int hh = 0; hh < 8; ++hh) {
        int h = h8 + hh;
        float s = Wb[h];
        for (int c = 0; c < 64; ++c) s += z[r][c] * w[h][c];
        hidden[(size_t)(i0 + r) * 64 + h] = s;
        hl[r][h] = s;
    }
    __syncthreads();
    if (tid < 64) {
        float s = 0.f, q2 = 0.f;
#pragma unroll
        for (int rr = 0; rr < 32; ++rr) {
            float v = hl[rr][tid];
            s += v; q2 += v * v;
        }
        bsum[blockIdx.x * 64 + tid] = s;
        bsq[blockIdx.x * 64 + tid] = q2;
    }
}

__global__ __launch_bounds__(64) void bn_stats(const float* __restrict__ bsum,
        const float* __restrict__ bsq, const float* __restrict__ gamma,
        const float* __restrict__ beta, float* __restrict__ bnc) {
    int h = threadIdx.x;
    float s = 0.f, q = 0.f;
    for (int b = 0; b < 256; ++b) { s += bsum[b * 64 + h]; q += bsq[b * 64 + h]; }
    float mean = s / 8192.0f;
    float var = q / 8192.0f - mean * mean;
    float inv = rsqrtf(var + 1e-5f);
    float sc = gamma[h] * inv;
    bnc[h] = sc;
    bnc[64 + h] = beta[h] - mean * sc;
}

__global__ __launch_bounds__(256) void head(const float* __restrict__ hidden,
        const float* __restrict__ bnc, const float* __restrict__ Mw,
        const float* __restrict__ Mb, float* __restrict__ out0) {
    __shared__ float a[32][65];
    __shared__ float w[32][65];
    __shared__ float o[32][33];
    __shared__ float rowm[32];
    int i0 = blockIdx.x * 32;
    int tid = threadIdx.x;
    for (int e = tid * 4; e < 2048; e += 1024) {
        f32x4 v = *(const f32x4*)(Mw + e);
        int oo = e >> 6, c = e & 63;
#pragma unroll
        for (int q = 0; q < 4; ++q) w[oo][c + q] = v[q];
    }
    int r = tid >> 3, h8 = (tid & 7) * 8;
    const float* hp = hidden + (size_t)(i0 + r) * 64 + h8;
#pragma unroll
    for (int q = 0; q < 8; ++q) {
        int h = h8 + q;
        float v = hp[q] * bnc[h] + bnc[64 + h];
        a[r][h] = fmaxf(v, 0.f);
    }
    __syncthreads();
    int o4 = (tid & 7) * 4;
#pragma unroll
    for (int q = 0; q < 4; ++q) {
        int oo = o4 + q;
        float s = Mb[oo];
        for (int c = 0; c < 64; ++c) s += a[r][c] * w[oo][c];
        o[r][oo] = s;
    }
    __syncthreads();
    if (tid < 32) {
        float m = -3.0e38f;
#pragma unroll
        for (int c = 0; c < 32; ++c) m = fmaxf(m, o[tid][c]);
        float se = 0.f;
#pragma unroll
        for (int c = 0; c < 32; ++c) se += expf(o[tid][c] - m);
        rowm[tid] = m + logf(se);
    }
    __syncthreads();
    f32x4 v;
#pragma unroll
    for (int q = 0; q < 4; ++q) v[q] = o[r][o4 + q] - rowm[r];
    *(f32x4*)(out0 + (size_t)(i0 + r) * 32 + o4) = v;
}

extern "C" void kernel_launch(void* const* d_in, const int* in_sizes, int n_in,
                              void* d_out, int out_size, void* d_ws, size_t ws_size,
                              hipStream_t stream) {
    const float* X   = (const float*)d_in[0];
    const float* La  = (const float*)d_in[1];
    const float* U   = (const float*)d_in[2];
    const float* ve  = (const float*)d_in[3];
    const float* ve2 = (const float*)d_in[4];
    const float* Ww  = (const float*)d_in[5];
    const float* Wb  = (const float*)d_in[6];
    const float* gam = (const float*)d_in[7];
    const float* bet = (const float*)d_in[8];
    const float* Mw  = (const float*)d_in[9];
    const float* Mb  = (const float*)d_in[10];
    float* out0 = (float*)d_out;
    float* hidden = (float*)d_out + (size_t)NN * 32;   // output 1 region

    char* ws = (char*)d_ws;
    float* V1   = (float*)ws;                             // 32 KB
    float* V2   = (float*)(ws + 32768);                   // 32 KB
    float* bsum = (float*)(ws + 65536);                   // 64 KB
    float* bsq  = (float*)(ws + 131072);                  // 64 KB
    float* bnc  = (float*)(ws + 196608);                  // 512 B
    unsigned short* FB = (unsigned short*)(ws + 262144);  // 1 MB frag-major bf16
    float* P    = (float*)(ws + (2u << 20));              // 16 MB [SK][NN][64]
    float* Pt   = (float*)(ws + (20u << 20));             // 16 MB [SK][64][NN]

    prep_v<<<32, 256, 0, stream>>>(La, ve, ve2, V1, V2);
    // FB = frag(X)
    reduce_t<<<256, 256, 0, stream>>>(X, 1, FB);
    // T1^T partials = X^T @ U
    spec_pass<1><<<dim3(NN / 64, SK), 256, 0, stream>>>(U, FB, Pt);
    // FB = frag(V1 .* T1)
    reduce2<<<256, 256, 0, stream>>>(Pt, V1, FB);
    // Z1 = U @ S1
    spec_pass<0><<<dim3(NN / 64, SK), 256, 0, stream>>>(U, FB, P);
    // FB = frag(Z1)
    reduce_t<<<256, 256, 0, stream>>>(P, SK, FB);
    // T2^T partials = Z1^T @ U
    spec_pass<1><<<dim3(NN / 64, SK), 256, 0, stream>>>(U, FB, Pt);
    // FB = frag(V2 .* T2)
    reduce2<<<256, 256, 0, stream>>>(Pt, V2, FB);
    // Z2 = U @ S2
    spec_pass<0><<<dim3(NN / 64, SK), 256, 0, stream>>>(U, FB, P);
    // hidden = Z2 @ Ww^T + Wb  (+ BN partial stats)
    reduce_linear<<<256, 256, 0, stream>>>(P, Ww, Wb, hidden, bsum, bsq);
    bn_stats<<<1, 64, 0, stream>>>(bsum, bsq, gam, bet, bnc);
    head<<<256, 256, 0, stream>>>(hidden, bnc, Mw, Mb, out0);
}